// Round 3
// baseline (269.516 us; speedup 1.0000x reference)
//
#include <hip/hip_runtime.h>
#include <math.h>

#define HDIM 256
#define KDIM 16
#define SDIM 200
#define BDIM 512
#define NROWS (BDIM * SDIM)   // 102400
#define TM 64                 // rows per block in kernel 1 (64KB LDS, 2 blk/CU)

typedef __bf16 bf16x8 __attribute__((ext_vector_type(8)));
typedef __bf16 bf16x4 __attribute__((ext_vector_type(4)));
typedef float  f32x4  __attribute__((ext_vector_type(4)));

// ---------------------------------------------------------------------------
// Fused pack: W1, W2, W3 -> fragment-ready split-bf16 layout
//   dst[((k>>3)*N + n)*8 + (k&7)] = hi/lo bf16 of W[k*N + n]
// ---------------------------------------------------------------------------
__global__ __launch_bounds__(256) void pack_all(
    const float* __restrict__ W1, const float* __restrict__ W2,
    const float* __restrict__ W3,
    __bf16* __restrict__ w1h, __bf16* __restrict__ w1l,
    __bf16* __restrict__ w2h, __bf16* __restrict__ w2l,
    __bf16* __restrict__ w3h, __bf16* __restrict__ w3l)
{
    int gid = blockIdx.x * 256 + threadIdx.x;
    const float* src;
    __bf16 *oh, *ol;
    int e, N;
    if (gid < 65536)       { src = W1; oh = w1h; ol = w1l; e = gid;          N = 256; }
    else if (gid < 131072) { src = W2; oh = w2h; ol = w2l; e = gid - 65536;  N = 256; }
    else if (gid < 135168) { src = W3; oh = w3h; ol = w3l; e = gid - 131072; N = 16;  }
    else return;

    int j  = e & 7;
    int n  = (e >> 3) & (N - 1);
    int kg = e >> 3; kg = (N == 256) ? (kg >> 8) : (kg >> 4);
    int k  = kg * 8 + j;
    float v = src[k * N + n];
    __bf16 h = (__bf16)v;
    oh[e] = h;
    ol[e] = (__bf16)(v - (float)h);
}

// ---------------------------------------------------------------------------
// Kernel 1 v9: TM 32->64. Each block now amortizes the full-W read (512KB
// of L2 traffic per block per 2 layers) over 64 rows instead of 32:
// W L2 traffic 1.6GB -> 0.8GB. mt loop 2->4 (b-fragments reused 4x; 48
// MFMA per kc per wave). a-frags loaded inside the mt loop to cap VGPRs.
// Swapped-operand MFMA epilogue (b64 LDS writes) kept from v8.
// ---------------------------------------------------------------------------
__global__ __launch_bounds__(256) void mlp_softk_mfma(
    const float* __restrict__ X, const int* __restrict__ mask,
    const __bf16* __restrict__ W1h, const __bf16* __restrict__ W1l,
    const float* __restrict__ b1,
    const __bf16* __restrict__ W2h, const __bf16* __restrict__ W2l,
    const float* __restrict__ b2,
    const __bf16* __restrict__ W3h, const __bf16* __restrict__ W3l,
    float* __restrict__ P)
{
    __shared__ __bf16 Ahi[TM * HDIM];   // 32 KB
    __shared__ __bf16 Alo[TM * HDIM];   // 32 KB

    const int tid  = threadIdx.x;
    const int lane = tid & 63;
    const int w    = tid >> 6;      // wave id: owns cols 64w..64w+63
    const int l15  = lane & 15;
    const int quad = lane >> 4;
    const long r0  = (long)blockIdx.x * TM;

    // ---- stage X tile -> LDS as split bf16 (swizzled) ----
    {
        const float4* Xt = (const float4*)(X + r0 * HDIM);
        #pragma unroll
        for (int t = 0; t < (TM * HDIM / 4) / 256; ++t) {
            int v4  = tid + t * 256;
            float4 f = Xt[v4];
            int row = v4 >> 6;            // 64 float4 per row
            int col = (v4 & 63) << 2;
            int kgs = (col >> 3) ^ (row & 31);
            int base = row * HDIM + kgs * 8 + (col & 7);
            __bf16 h0 = (__bf16)f.x, h1 = (__bf16)f.y,
                   h2 = (__bf16)f.z, h3 = (__bf16)f.w;
            bf16x4 hv = {h0, h1, h2, h3};
            bf16x4 lv = {(__bf16)(f.x - (float)h0), (__bf16)(f.y - (float)h1),
                         (__bf16)(f.z - (float)h2), (__bf16)(f.w - (float)h3)};
            *(bf16x4*)(&Ahi[base]) = hv;
            *(bf16x4*)(&Alo[base]) = lv;
        }
    }
    __syncthreads();

    f32x4 acc[4][4];

    auto layer = [&](const __bf16* __restrict__ Wh, const __bf16* __restrict__ Wl,
                     const float* __restrict__ bias) {
        #pragma unroll
        for (int mt = 0; mt < 4; ++mt)
            #pragma unroll
            for (int nt = 0; nt < 4; ++nt)
                acc[mt][nt] = (f32x4){0.f, 0.f, 0.f, 0.f};

        #pragma unroll
        for (int kc = 0; kc < 8; ++kc) {
            bf16x8 bh[4], bl[4];
            #pragma unroll
            for (int nt = 0; nt < 4; ++nt) {
                int n  = w * 64 + nt * 16 + l15;
                int kg = kc * 4 + quad;
                bh[nt] = *(const bf16x8*)(Wh + (kg * HDIM + n) * 8);
                bl[nt] = *(const bf16x8*)(Wl + (kg * HDIM + n) * 8);
            }
            #pragma unroll
            for (int mt = 0; mt < 4; ++mt) {
                int row = mt * 16 + l15;
                int kgs = (kc * 4 + quad) ^ (row & 31);
                bf16x8 ah = *(const bf16x8*)(&Ahi[row * HDIM + kgs * 8]);
                bf16x8 al = *(const bf16x8*)(&Alo[row * HDIM + kgs * 8]);
                // SWAPPED: A-operand = W fragment, B-operand = X fragment.
                #pragma unroll
                for (int nt = 0; nt < 4; ++nt) {
                    acc[mt][nt] = __builtin_amdgcn_mfma_f32_16x16x32_bf16(
                        bh[nt], ah, acc[mt][nt], 0, 0, 0);
                    acc[mt][nt] = __builtin_amdgcn_mfma_f32_16x16x32_bf16(
                        bh[nt], al, acc[mt][nt], 0, 0, 0);
                    acc[mt][nt] = __builtin_amdgcn_mfma_f32_16x16x32_bf16(
                        bl[nt], ah, acc[mt][nt], 0, 0, 0);
                }
            }
        }
        __syncthreads();   // everyone done reading A before overwrite

        // C layout (swapped): m = mt*16 + (lane&15), n = w*64 + nt*16 + quad*4 + r
        // -> regs r=0..3 are 4 consecutive h-columns: one bf16x4 write per array.
        f32x4 bias4[4];
        #pragma unroll
        for (int nt = 0; nt < 4; ++nt)
            bias4[nt] = *(const f32x4*)(bias + w * 64 + nt * 16 + quad * 4);

        #pragma unroll
        for (int mt = 0; mt < 4; ++mt)
            #pragma unroll
            for (int nt = 0; nt < 4; ++nt) {
                int m   = mt * 16 + l15;
                int g   = w * 8 + nt * 2 + (quad >> 1);          // n>>3
                int idx = m * HDIM + (((g ^ (m & 31)) * 8) + (quad & 1) * 4);
                bf16x4 hv, lv;
                #pragma unroll
                for (int r = 0; r < 4; ++r) {
                    float v = fmaxf(acc[mt][nt][r] + bias4[nt][r], 0.f);
                    __bf16 h = (__bf16)v;
                    hv[r] = h;
                    lv[r] = (__bf16)(v - (float)h);
                }
                *(bf16x4*)(&Ahi[idx]) = hv;
                *(bf16x4*)(&Alo[idx]) = lv;
            }
        __syncthreads();
    };

    layer(W1h, W1l, b1);
    layer(W2h, W2l, b2);

    // ---- logits: each wave handles one 16-row m-tile (TM=64 -> 4 waves) ----
    // (unswapped: want k across lanes for the shfl_xor softmax)
    {
        f32x4 lg = {0.f, 0.f, 0.f, 0.f};
        #pragma unroll
        for (int kc = 0; kc < 8; ++kc) {
            int row = w * 16 + l15;
            int kg  = kc * 4 + quad;
            int kgs = kg ^ (row & 31);
            bf16x8 ah = *(const bf16x8*)(&Ahi[row * HDIM + kgs * 8]);
            bf16x8 al = *(const bf16x8*)(&Alo[row * HDIM + kgs * 8]);
            bf16x8 bh = *(const bf16x8*)(W3h + (kg * KDIM + l15) * 8);
            bf16x8 bl = *(const bf16x8*)(W3l + (kg * KDIM + l15) * 8);
            lg = __builtin_amdgcn_mfma_f32_16x16x32_bf16(ah, bh, lg, 0, 0, 0);
            lg = __builtin_amdgcn_mfma_f32_16x16x32_bf16(al, bh, lg, 0, 0, 0);
            lg = __builtin_amdgcn_mfma_f32_16x16x32_bf16(ah, bl, lg, 0, 0, 0);
        }

        // softmax over k: 16 lanes of a quad-group hold the 16 cols of a row
        #pragma unroll
        for (int r = 0; r < 4; ++r) {
            float v  = lg[r];
            float mx = v;
            mx = fmaxf(mx, __shfl_xor(mx, 1));
            mx = fmaxf(mx, __shfl_xor(mx, 2));
            mx = fmaxf(mx, __shfl_xor(mx, 4));
            mx = fmaxf(mx, __shfl_xor(mx, 8));
            float e = __expf(v - mx);
            float s = e;
            s += __shfl_xor(s, 1);
            s += __shfl_xor(s, 2);
            s += __shfl_xor(s, 4);
            s += __shfl_xor(s, 8);
            int grow = (int)r0 + w * 16 + quad * 4 + r;
            int mv   = mask[grow];
            float ov = mv ? (e / s) * 0.25f : -2500.0f;   // (-10000)/sqrt(16)
            P[(long)grow * KDIM + l15] = ov;
        }
    }
}

// ---------------------------------------------------------------------------
// Kernel 2 (UNCHANGED): 512 threads = 8 waves = (s-quarter sq, k-half kh).
// ---------------------------------------------------------------------------
__global__ __launch_bounds__(512) void softs_agg_kernel(
    const float* __restrict__ X, const float* __restrict__ tf,
    const float* __restrict__ P, float* __restrict__ out)
{
    __shared__ float wl[SDIM * KDIM];          // 12.8 KB
    __shared__ float tfl[SDIM];                // 0.8 KB
    __shared__ float invk[KDIM];
    __shared__ float red[6 * 8 * HDIM];        // 48 KB: slot (sq-1)*2+kh
    float* psum = red;                         // alias (dead before red use)

    const int tid = threadIdx.x;
    const int b   = blockIdx.x;

    // ---- phase 1: column softmax over S (exp(-2500)==0 handles the mask) ----
    const float* Pb = P + (long)b * SDIM * KDIM;
    float ps = 0.f;
    #pragma unroll
    for (int t = 0; t < 7; ++t) {
        int i = tid + t * 512;
        if (i < SDIM * KDIM) {
            float e = __expf(Pb[i]);
            wl[i] = e;
            ps += e;
        }
    }
    psum[tid] = ps;
    if (tid < SDIM) tfl[tid] = tf[b * SDIM + tid];
    __syncthreads();

    if (tid < KDIM) {
        float s = 0.f;
        #pragma unroll
        for (int g = 0; g < 32; ++g) s += psum[tid + g * 16];   // 512%16==0
        invk[tid] = 1.f / s;
    }
    __syncthreads();

    #pragma unroll
    for (int t = 0; t < 7; ++t) {
        int i = tid + t * 512;
        if (i < SDIM * KDIM) wl[i] *= tfl[i >> 4] * invk[i & 15];
    }
    __syncthreads();

    // ---- phase 2: out[b,k,h] = sum_s X[b,s,h] * wl[s,k] ----
    const int wv = tid >> 6;
    const int sq = wv >> 1;      // s-quarter: [50*sq, 50*sq+50)
    const int kh = wv & 1;       // k-half: k in [8*kh, 8*kh+8)
    const int ln = tid & 63;     // lane -> h-cols 4*ln..4*ln+3

    f32x4 acc[8];
    #pragma unroll
    for (int j = 0; j < 8; ++j) acc[j] = (f32x4){0.f, 0.f, 0.f, 0.f};

    const f32x4* Xb4 = (const f32x4*)(X + (long)b * SDIM * HDIM);
    const f32x4* wl4 = (const f32x4*)wl;
    const int s0 = sq * 50;
    #pragma unroll 5
    for (int si = 0; si < 50; ++si) {
        int s = s0 + si;
        f32x4 x  = Xb4[s * 64 + ln];             // 1KB coalesced per wave
        f32x4 d0 = wl4[s * 4 + 2 * kh + 0];      // wave-uniform LDS b128
        f32x4 d1 = wl4[s * 4 + 2 * kh + 1];
        #pragma unroll
        for (int j = 0; j < 4; ++j) {
            acc[j]     += x * d0[j];             // k = 8kh + j
            acc[4 + j] += x * d1[j];             // k = 8kh + 4 + j
        }
    }

    // ---- tree reduce over s-quarters: sq>0 deposit, sq==0 sums + stores ----
    if (sq > 0) {
        float* rp = red + (((sq - 1) * 2 + kh) * 8) * HDIM;
        #pragma unroll
        for (int j = 0; j < 8; ++j)
            *(f32x4*)(rp + j * HDIM + 4 * ln) = acc[j];
    }
    __syncthreads();
    if (sq == 0) {
        #pragma unroll
        for (int p = 0; p < 3; ++p) {
            const float* rp = red + ((p * 2 + kh) * 8) * HDIM;
            #pragma unroll
            for (int j = 0; j < 8; ++j)
                acc[j] += *(const f32x4*)(rp + j * HDIM + 4 * ln);
        }
        float* ob = out + (long)b * KDIM * HDIM + kh * 8 * HDIM;
        #pragma unroll
        for (int j = 0; j < 8; ++j)
            *(f32x4*)(ob + j * HDIM + 4 * ln) = acc[j];
    }
}

extern "C" void kernel_launch(void* const* d_in, const int* in_sizes, int n_in,
                              void* d_out, int out_size, void* d_ws, size_t ws_size,
                              hipStream_t stream) {
    (void)in_sizes; (void)n_in; (void)out_size; (void)ws_size;
    const float* X    = (const float*)d_in[0];
    const int*   mask = (const int*)  d_in[1];
    const float* tf   = (const float*)d_in[2];
    const float* W1   = (const float*)d_in[3];
    const float* b1   = (const float*)d_in[4];
    const float* W2   = (const float*)d_in[5];
    const float* b2   = (const float*)d_in[6];
    const float* W3   = (const float*)d_in[7];
    float* out = (float*)d_out;

    char* ws = (char*)d_ws;
    float*  P   = (float*)ws;                          // 102400*16*4 = 6,553,600 B
    __bf16* w1h = (__bf16*)(ws + 6553600);             // 65536 elems each
    __bf16* w1l = w1h + 65536;
    __bf16* w2h = w1l + 65536;
    __bf16* w2l = w2h + 65536;
    __bf16* w3h = w2l + 65536;                         // 4096 elems each
    __bf16* w3l = w3h + 4096;

    pack_all<<<528, 256, 0, stream>>>(W1, W2, W3, w1h, w1l, w2h, w2l, w3h, w3l);
    mlp_softk_mfma<<<NROWS / TM, 256, 0, stream>>>(X, mask, w1h, w1l, b1,
                                                   w2h, w2l, b2, w3h, w3l, P);
    softs_agg_kernel<<<BDIM, 512, 0, stream>>>(X, tf, P, out);
}

// Round 4
// 263.821 us; speedup vs baseline: 1.0216x; 1.0216x over previous
//
#include <hip/hip_runtime.h>
#include <math.h>

#define HDIM 256
#define KDIM 16
#define SDIM 200
#define BDIM 512
#define NROWS (BDIM * SDIM)   // 102400
#define TM 32                 // rows per block in kernel 1 (32KB LDS)

typedef __bf16 bf16x8 __attribute__((ext_vector_type(8)));
typedef __bf16 bf16x4 __attribute__((ext_vector_type(4)));
typedef float  f32x4  __attribute__((ext_vector_type(4)));

// ---------------------------------------------------------------------------
// Fused pack. W1/W2 -> INTERLEAVED hi|lo split-bf16 fragment layout:
//   wi[(kg*256 + n)*16 + j]     = hi bf16 of W[(kg*8+j)*256 + n]
//   wi[(kg*256 + n)*16 + 8 + j] = lo bf16 (residual)
// (one L2 stream, hi/lo 16B-adjacent). W3 stays split h/l as before.
// ---------------------------------------------------------------------------
__global__ __launch_bounds__(256) void pack_all(
    const float* __restrict__ W1, const float* __restrict__ W2,
    const float* __restrict__ W3,
    __bf16* __restrict__ w1i, __bf16* __restrict__ w2i,
    __bf16* __restrict__ w3h, __bf16* __restrict__ w3l)
{
    int gid = blockIdx.x * 256 + threadIdx.x;
    if (gid < 131072) {
        int sel = gid >> 16;                 // 0: W1, 1: W2
        int e   = gid & 65535;
        const float* src = sel ? W2 : W1;
        __bf16*      dst = sel ? w2i : w1i;
        int j  = e & 7;
        int n  = (e >> 3) & 255;
        int kg = e >> 11;
        float v  = src[(kg * 8 + j) * 256 + n];
        __bf16 h = (__bf16)v;
        dst[(kg * 256 + n) * 16 + j]     = h;
        dst[(kg * 256 + n) * 16 + 8 + j] = (__bf16)(v - (float)h);
    } else if (gid < 135168) {
        int e  = gid - 131072;
        int j  = e & 7;
        int n  = (e >> 3) & 15;
        int kg = e >> 7;
        float v  = W3[(kg * 8 + j) * 16 + n];
        __bf16 h = (__bf16)v;
        w3h[e] = h;
        w3l[e] = (__bf16)(v - (float)h);
    }
}

// ---------------------------------------------------------------------------
// Kernel 1 v10: TM back to 32 (measured best). Two schedule changes:
//  (a) W hi/lo interleaved -> one stream, one base addr per fragment pair.
//  (b) EXPLICIT cross-kc W-fragment prefetch: fh/fl[2][4] double buffer,
//      kc+1's 8 global loads issued BEFORE kc's ds_read+MFMA block, so
//      they stay in flight across the compute phase (source-level
//      approximation of counted vmcnt). Indices constant-fold under full
//      unroll (no scratch). Numerics bit-identical to v8/v9.
// ---------------------------------------------------------------------------
__global__ __launch_bounds__(256) void mlp_softk_mfma(
    const float* __restrict__ X, const int* __restrict__ mask,
    const __bf16* __restrict__ W1i, const float* __restrict__ b1,
    const __bf16* __restrict__ W2i, const float* __restrict__ b2,
    const __bf16* __restrict__ W3h, const __bf16* __restrict__ W3l,
    float* __restrict__ P)
{
    __shared__ __bf16 Ahi[TM * HDIM];   // 16 KB
    __shared__ __bf16 Alo[TM * HDIM];   // 16 KB

    const int tid  = threadIdx.x;
    const int lane = tid & 63;
    const int w    = tid >> 6;      // wave id: owns cols 64w..64w+63
    const int l15  = lane & 15;
    const int quad = lane >> 4;
    const long r0  = (long)blockIdx.x * TM;

    // ---- stage X tile -> LDS as split bf16 (swizzled) ----
    {
        const float4* Xt = (const float4*)(X + r0 * HDIM);
        #pragma unroll
        for (int t = 0; t < (TM * HDIM / 4) / 256; ++t) {
            int v4  = tid + t * 256;
            float4 f = Xt[v4];
            int row = v4 >> 6;            // 64 float4 per row
            int col = (v4 & 63) << 2;
            int kgs = (col >> 3) ^ (row & 31);
            int base = row * HDIM + kgs * 8 + (col & 7);
            __bf16 h0 = (__bf16)f.x, h1 = (__bf16)f.y,
                   h2 = (__bf16)f.z, h3 = (__bf16)f.w;
            bf16x4 hv = {h0, h1, h2, h3};
            bf16x4 lv = {(__bf16)(f.x - (float)h0), (__bf16)(f.y - (float)h1),
                         (__bf16)(f.z - (float)h2), (__bf16)(f.w - (float)h3)};
            *(bf16x4*)(&Ahi[base]) = hv;
            *(bf16x4*)(&Alo[base]) = lv;
        }
    }
    __syncthreads();

    f32x4 acc[2][4];

    auto layer = [&](const __bf16* __restrict__ Wi, const float* __restrict__ bias) {
        #pragma unroll
        for (int mt = 0; mt < 2; ++mt)
            #pragma unroll
            for (int nt = 0; nt < 4; ++nt)
                acc[mt][nt] = (f32x4){0.f, 0.f, 0.f, 0.f};

        bf16x8 fh[2][4], fl[2][4];
        // preload kc = 0
        #pragma unroll
        for (int nt = 0; nt < 4; ++nt) {
            int n = w * 64 + nt * 16 + l15;
            const __bf16* p = Wi + ((long)(quad * HDIM + n)) * 16;
            fh[0][nt] = *(const bf16x8*)(p);
            fl[0][nt] = *(const bf16x8*)(p + 8);
        }

        #pragma unroll
        for (int kc = 0; kc < 8; ++kc) {
            const int cur = kc & 1;
            const int nxt = cur ^ 1;
            if (kc < 7) {   // issue kc+1's loads before kc's compute
                #pragma unroll
                for (int nt = 0; nt < 4; ++nt) {
                    int n = w * 64 + nt * 16 + l15;
                    const __bf16* p = Wi + ((long)(((kc + 1) * 4 + quad) * HDIM + n)) * 16;
                    fh[nxt][nt] = *(const bf16x8*)(p);
                    fl[nxt][nt] = *(const bf16x8*)(p + 8);
                }
            }
            #pragma unroll
            for (int mt = 0; mt < 2; ++mt) {
                int row = mt * 16 + l15;
                int kgs = (kc * 4 + quad) ^ (row & 31);
                bf16x8 ah = *(const bf16x8*)(&Ahi[row * HDIM + kgs * 8]);
                bf16x8 al = *(const bf16x8*)(&Alo[row * HDIM + kgs * 8]);
                // SWAPPED: A-operand = W fragment, B-operand = X fragment.
                #pragma unroll
                for (int nt = 0; nt < 4; ++nt) {
                    acc[mt][nt] = __builtin_amdgcn_mfma_f32_16x16x32_bf16(
                        fh[cur][nt], ah, acc[mt][nt], 0, 0, 0);
                    acc[mt][nt] = __builtin_amdgcn_mfma_f32_16x16x32_bf16(
                        fh[cur][nt], al, acc[mt][nt], 0, 0, 0);
                    acc[mt][nt] = __builtin_amdgcn_mfma_f32_16x16x32_bf16(
                        fl[cur][nt], ah, acc[mt][nt], 0, 0, 0);
                }
            }
        }
        __syncthreads();   // everyone done reading A before overwrite

        // C layout (swapped): m = mt*16 + (lane&15), n = w*64 + nt*16 + quad*4 + r
        // -> regs r=0..3 are 4 consecutive h-columns: one bf16x4 write per array.
        f32x4 bias4[4];
        #pragma unroll
        for (int nt = 0; nt < 4; ++nt)
            bias4[nt] = *(const f32x4*)(bias + w * 64 + nt * 16 + quad * 4);

        #pragma unroll
        for (int mt = 0; mt < 2; ++mt)
            #pragma unroll
            for (int nt = 0; nt < 4; ++nt) {
                int m   = mt * 16 + l15;
                int g   = w * 8 + nt * 2 + (quad >> 1);          // col>>3
                int idx = m * HDIM + (((g ^ (m & 31)) * 8) + (quad & 1) * 4);
                bf16x4 hv, lv;
                #pragma unroll
                for (int r = 0; r < 4; ++r) {
                    float v = fmaxf(acc[mt][nt][r] + bias4[nt][r], 0.f);
                    __bf16 h = (__bf16)v;
                    hv[r] = h;
                    lv[r] = (__bf16)(v - (float)h);
                }
                *(bf16x4*)(&Ahi[idx]) = hv;
                *(bf16x4*)(&Alo[idx]) = lv;
            }
        __syncthreads();
    };

    layer(W1i, b1);
    layer(W2i, b2);

    // ---- logits: waves 0,1 each handle one 16-row m-tile (TM=32) ----
    // (unswapped: want k across lanes for the shfl_xor softmax)
    if (w < 2) {
        f32x4 lg = {0.f, 0.f, 0.f, 0.f};
        #pragma unroll
        for (int kc = 0; kc < 8; ++kc) {
            int row = w * 16 + l15;
            int kg  = kc * 4 + quad;
            int kgs = kg ^ (row & 31);
            bf16x8 ah = *(const bf16x8*)(&Ahi[row * HDIM + kgs * 8]);
            bf16x8 al = *(const bf16x8*)(&Alo[row * HDIM + kgs * 8]);
            bf16x8 bh = *(const bf16x8*)(W3h + (kg * KDIM + l15) * 8);
            bf16x8 bl = *(const bf16x8*)(W3l + (kg * KDIM + l15) * 8);
            lg = __builtin_amdgcn_mfma_f32_16x16x32_bf16(ah, bh, lg, 0, 0, 0);
            lg = __builtin_amdgcn_mfma_f32_16x16x32_bf16(al, bh, lg, 0, 0, 0);
            lg = __builtin_amdgcn_mfma_f32_16x16x32_bf16(ah, bl, lg, 0, 0, 0);
        }

        // softmax over k: 16 lanes of a quad-group hold the 16 cols of a row
        #pragma unroll
        for (int r = 0; r < 4; ++r) {
            float v  = lg[r];
            float mx = v;
            mx = fmaxf(mx, __shfl_xor(mx, 1));
            mx = fmaxf(mx, __shfl_xor(mx, 2));
            mx = fmaxf(mx, __shfl_xor(mx, 4));
            mx = fmaxf(mx, __shfl_xor(mx, 8));
            float e = __expf(v - mx);
            float s = e;
            s += __shfl_xor(s, 1);
            s += __shfl_xor(s, 2);
            s += __shfl_xor(s, 4);
            s += __shfl_xor(s, 8);
            int grow = (int)r0 + w * 16 + quad * 4 + r;
            int mv   = mask[grow];
            float ov = mv ? (e / s) * 0.25f : -2500.0f;   // (-10000)/sqrt(16)
            P[(long)grow * KDIM + l15] = ov;
        }
    }
}

// ---------------------------------------------------------------------------
// Kernel 2 (UNCHANGED): 512 threads = 8 waves = (s-quarter sq, k-half kh).
// ---------------------------------------------------------------------------
__global__ __launch_bounds__(512) void softs_agg_kernel(
    const float* __restrict__ X, const float* __restrict__ tf,
    const float* __restrict__ P, float* __restrict__ out)
{
    __shared__ float wl[SDIM * KDIM];          // 12.8 KB
    __shared__ float tfl[SDIM];                // 0.8 KB
    __shared__ float invk[KDIM];
    __shared__ float red[6 * 8 * HDIM];        // 48 KB: slot (sq-1)*2+kh
    float* psum = red;                         // alias (dead before red use)

    const int tid = threadIdx.x;
    const int b   = blockIdx.x;

    // ---- phase 1: column softmax over S (exp(-2500)==0 handles the mask) ----
    const float* Pb = P + (long)b * SDIM * KDIM;
    float ps = 0.f;
    #pragma unroll
    for (int t = 0; t < 7; ++t) {
        int i = tid + t * 512;
        if (i < SDIM * KDIM) {
            float e = __expf(Pb[i]);
            wl[i] = e;
            ps += e;
        }
    }
    psum[tid] = ps;
    if (tid < SDIM) tfl[tid] = tf[b * SDIM + tid];
    __syncthreads();

    if (tid < KDIM) {
        float s = 0.f;
        #pragma unroll
        for (int g = 0; g < 32; ++g) s += psum[tid + g * 16];   // 512%16==0
        invk[tid] = 1.f / s;
    }
    __syncthreads();

    #pragma unroll
    for (int t = 0; t < 7; ++t) {
        int i = tid + t * 512;
        if (i < SDIM * KDIM) wl[i] *= tfl[i >> 4] * invk[i & 15];
    }
    __syncthreads();

    // ---- phase 2: out[b,k,h] = sum_s X[b,s,h] * wl[s,k] ----
    const int wv = tid >> 6;
    const int sq = wv >> 1;      // s-quarter: [50*sq, 50*sq+50)
    const int kh = wv & 1;       // k-half: k in [8*kh, 8*kh+8)
    const int ln = tid & 63;     // lane -> h-cols 4*ln..4*ln+3

    f32x4 acc[8];
    #pragma unroll
    for (int j = 0; j < 8; ++j) acc[j] = (f32x4){0.f, 0.f, 0.f, 0.f};

    const f32x4* Xb4 = (const f32x4*)(X + (long)b * SDIM * HDIM);
    const f32x4* wl4 = (const f32x4*)wl;
    const int s0 = sq * 50;
    #pragma unroll 5
    for (int si = 0; si < 50; ++si) {
        int s = s0 + si;
        f32x4 x  = Xb4[s * 64 + ln];             // 1KB coalesced per wave
        f32x4 d0 = wl4[s * 4 + 2 * kh + 0];      // wave-uniform LDS b128
        f32x4 d1 = wl4[s * 4 + 2 * kh + 1];
        #pragma unroll
        for (int j = 0; j < 4; ++j) {
            acc[j]     += x * d0[j];             // k = 8kh + j
            acc[4 + j] += x * d1[j];             // k = 8kh + 4 + j
        }
    }

    // ---- tree reduce over s-quarters: sq>0 deposit, sq==0 sums + stores ----
    if (sq > 0) {
        float* rp = red + (((sq - 1) * 2 + kh) * 8) * HDIM;
        #pragma unroll
        for (int j = 0; j < 8; ++j)
            *(f32x4*)(rp + j * HDIM + 4 * ln) = acc[j];
    }
    __syncthreads();
    if (sq == 0) {
        #pragma unroll
        for (int p = 0; p < 3; ++p) {
            const float* rp = red + ((p * 2 + kh) * 8) * HDIM;
            #pragma unroll
            for (int j = 0; j < 8; ++j)
                acc[j] += *(const f32x4*)(rp + j * HDIM + 4 * ln);
        }
        float* ob = out + (long)b * KDIM * HDIM + kh * 8 * HDIM;
        #pragma unroll
        for (int j = 0; j < 8; ++j)
            *(f32x4*)(ob + j * HDIM + 4 * ln) = acc[j];
    }
}

extern "C" void kernel_launch(void* const* d_in, const int* in_sizes, int n_in,
                              void* d_out, int out_size, void* d_ws, size_t ws_size,
                              hipStream_t stream) {
    (void)in_sizes; (void)n_in; (void)out_size; (void)ws_size;
    const float* X    = (const float*)d_in[0];
    const int*   mask = (const int*)  d_in[1];
    const float* tf   = (const float*)d_in[2];
    const float* W1   = (const float*)d_in[3];
    const float* b1   = (const float*)d_in[4];
    const float* W2   = (const float*)d_in[5];
    const float* b2   = (const float*)d_in[6];
    const float* W3   = (const float*)d_in[7];
    float* out = (float*)d_out;

    char* ws = (char*)d_ws;
    float*  P   = (float*)ws;                          // 102400*16*4 = 6,553,600 B
    __bf16* w1i = (__bf16*)(ws + 6553600);             // 131072 elems (interleaved)
    __bf16* w2i = w1i + 131072;
    __bf16* w3h = w2i + 131072;                        // 4096 elems each
    __bf16* w3l = w3h + 4096;

    pack_all<<<528, 256, 0, stream>>>(W1, W2, W3, w1i, w2i, w3h, w3l);
    mlp_softk_mfma<<<NROWS / TM, 256, 0, stream>>>(X, mask, w1i, b1,
                                                   w2i, b2, w3h, w3l, P);
    softs_agg_kernel<<<BDIM, 512, 0, stream>>>(X, tf, P, out);
}

// Round 5
// 260.951 us; speedup vs baseline: 1.0328x; 1.0110x over previous
//
#include <hip/hip_runtime.h>
#include <math.h>

#define HDIM 256
#define KDIM 16
#define SDIM 200
#define BDIM 512
#define NROWS (BDIM * SDIM)   // 102400
#define TM 32                 // rows per block in kernel 1

typedef __bf16 bf16x8 __attribute__((ext_vector_type(8)));
typedef __bf16 bf16x4 __attribute__((ext_vector_type(4)));
typedef float  f32x4  __attribute__((ext_vector_type(4)));

// async global->LDS, 16B per lane, dest = wave-uniform base + lane*16
#define GLL(gp, lp) __builtin_amdgcn_global_load_lds(                      \
    (const __attribute__((address_space(1))) void*)(gp),                   \
    (__attribute__((address_space(3))) void*)(lp), 16, 0, 0)

// ---------------------------------------------------------------------------
// Fused pack. W1/W2 -> INTERLEAVED hi|lo split-bf16 fragment layout:
//   wi[(kg*256 + n)*16 + j]     = hi bf16 of W[(kg*8+j)*256 + n]
//   wi[(kg*256 + n)*16 + 8 + j] = lo bf16 (residual)
// W3 stays split h/l.
// ---------------------------------------------------------------------------
__global__ __launch_bounds__(256) void pack_all(
    const float* __restrict__ W1, const float* __restrict__ W2,
    const float* __restrict__ W3,
    __bf16* __restrict__ w1i, __bf16* __restrict__ w2i,
    __bf16* __restrict__ w3h, __bf16* __restrict__ w3l)
{
    int gid = blockIdx.x * 256 + threadIdx.x;
    if (gid < 131072) {
        int sel = gid >> 16;                 // 0: W1, 1: W2
        int e   = gid & 65535;
        const float* src = sel ? W2 : W1;
        __bf16*      dst = sel ? w2i : w1i;
        int j  = e & 7;
        int n  = (e >> 3) & 255;
        int kg = e >> 11;
        float v  = src[(kg * 8 + j) * 256 + n];
        __bf16 h = (__bf16)v;
        dst[(kg * 256 + n) * 16 + j]     = h;
        dst[(kg * 256 + n) * 16 + 8 + j] = (__bf16)(v - (float)h);
    } else if (gid < 135168) {
        int e  = gid - 131072;
        int j  = e & 7;
        int n  = (e >> 3) & 15;
        int kg = e >> 7;
        float v  = W3[(kg * 8 + j) * 16 + n];
        __bf16 h = (__bf16)v;
        w3h[e] = h;
        w3l[e] = (__bf16)(v - (float)h);
    }
}

// ---------------------------------------------------------------------------
// Kernel 1 v11: counted-vmcnt W pipeline through a wave-private LDS FIFO.
//  - W fragments staged half-kc at a time (4KB/wave batch) via
//    global_load_lds (side-effecting intrinsic: compiler can't sink it).
//  - Ring of 3 slots, 2 batches in flight; inline-asm s_waitcnt vmcnt(8)
//    (never 0 mid-loop) + sched_barrier(0) per rule #18.
//  - FIFO is wave-private: each lane reads back exactly the 16B chunks it
//    DMA'd -> ZERO barriers in the k-loop. vmcnt retires in issue order,
//    so "<=8 outstanding" guarantees batch b landed even if the compiler
//    interleaves its own vmem ops.
//  - LDS: 32KB A-tile + 48KB FIFO = 80KB -> 2 blocks/CU.
// Numerics bit-identical to v8/v9/v10 (same split-bf16 3-pass MFMA).
// ---------------------------------------------------------------------------
__global__ __launch_bounds__(256) void mlp_softk_mfma(
    const float* __restrict__ X, const int* __restrict__ mask,
    const __bf16* __restrict__ W1i, const float* __restrict__ b1,
    const __bf16* __restrict__ W2i, const float* __restrict__ b2,
    const __bf16* __restrict__ W3h, const __bf16* __restrict__ W3l,
    float* __restrict__ P)
{
    __shared__ __bf16 Ahi[TM * HDIM];     // 16 KB
    __shared__ __bf16 Alo[TM * HDIM];     // 16 KB
    __shared__ __bf16 Wf[4 * 3 * 2048];   // 48 KB: 4 waves x 3 slots x 4KB

    const int tid  = threadIdx.x;
    const int lane = tid & 63;
    const int w    = tid >> 6;      // wave id: owns cols 64w..64w+63
    const int l15  = lane & 15;
    const int quad = lane >> 4;
    const long r0  = (long)blockIdx.x * TM;

    __bf16* Wfw = &Wf[w * 6144];    // this wave's 3-slot FIFO (elems)

    // ---- stage X tile -> LDS as split bf16 (swizzled) ----
    {
        const float4* Xt = (const float4*)(X + r0 * HDIM);
        #pragma unroll
        for (int t = 0; t < (TM * HDIM / 4) / 256; ++t) {
            int v4  = tid + t * 256;
            float4 f = Xt[v4];
            int row = v4 >> 6;            // 64 float4 per row
            int col = (v4 & 63) << 2;
            int kgs = (col >> 3) ^ (row & 31);
            int base = row * HDIM + kgs * 8 + (col & 7);
            __bf16 h0 = (__bf16)f.x, h1 = (__bf16)f.y,
                   h2 = (__bf16)f.z, h3 = (__bf16)f.w;
            bf16x4 hv = {h0, h1, h2, h3};
            bf16x4 lv = {(__bf16)(f.x - (float)h0), (__bf16)(f.y - (float)h1),
                         (__bf16)(f.z - (float)h2), (__bf16)(f.w - (float)h3)};
            *(bf16x4*)(&Ahi[base]) = hv;
            *(bf16x4*)(&Alo[base]) = lv;
        }
    }
    __syncthreads();

    f32x4 acc[2][4];

    // issue one half-kc batch (4 x global_load_lds = 4KB/wave) into slot b%3
    auto stage = [&](const __bf16* __restrict__ Wi, int b) {
        const int kc = b >> 1, s = b % 3, hf = b & 1;
        #pragma unroll
        for (int nt2 = 0; nt2 < 2; ++nt2) {
            const int nt = hf * 2 + nt2;
            const __bf16* g = Wi +
                ((long)(kc * 4 + quad) * HDIM + (w * 64 + nt * 16 + l15)) * 16;
            __bf16* lb = Wfw + s * 2048 + nt2 * 1024;   // wave-uniform base
            GLL(g,     lb);        // hi 16B -> base + lane*16
            GLL(g + 8, lb + 512);  // lo 16B -> base+1KB + lane*16
        }
    };

    auto layer = [&](const __bf16* __restrict__ Wi, const float* __restrict__ bias) {
        #pragma unroll
        for (int mt = 0; mt < 2; ++mt)
            #pragma unroll
            for (int nt = 0; nt < 4; ++nt)
                acc[mt][nt] = (f32x4){0.f, 0.f, 0.f, 0.f};

        stage(Wi, 0);
        stage(Wi, 1);

        bf16x8 ahr[2], alr[2];
        #pragma unroll
        for (int b = 0; b < 16; ++b) {
            const int kc = b >> 1, s = b % 3, hf = b & 1;
            if (b < 14) stage(Wi, b + 2);
            // counted wait: 2 batches (8 ops) stay in flight; drain only at end
            if (b < 14)       { asm volatile("s_waitcnt vmcnt(8)" ::: "memory"); }
            else if (b == 14) { asm volatile("s_waitcnt vmcnt(4)" ::: "memory"); }
            else              { asm volatile("s_waitcnt vmcnt(0)" ::: "memory"); }
            __builtin_amdgcn_sched_barrier(0);

            if (hf == 0) {  // A fragments shared by both halves of this kc
                #pragma unroll
                for (int mt = 0; mt < 2; ++mt) {
                    int row = mt * 16 + l15;
                    int kgs = (kc * 4 + quad) ^ (row & 31);
                    ahr[mt] = *(const bf16x8*)(&Ahi[row * HDIM + kgs * 8]);
                    alr[mt] = *(const bf16x8*)(&Alo[row * HDIM + kgs * 8]);
                }
            }
            bf16x8 bh[2], bl[2];
            #pragma unroll
            for (int nt2 = 0; nt2 < 2; ++nt2) {
                const __bf16* sl = Wfw + s * 2048 + nt2 * 1024 + lane * 8;
                bh[nt2] = *(const bf16x8*)(sl);
                bl[nt2] = *(const bf16x8*)(sl + 512);
            }
            // pass-outer order: 4-wide spacing between dependent MFMAs
            #pragma unroll
            for (int mt = 0; mt < 2; ++mt)
                #pragma unroll
                for (int nt2 = 0; nt2 < 2; ++nt2)
                    acc[mt][hf * 2 + nt2] = __builtin_amdgcn_mfma_f32_16x16x32_bf16(
                        bh[nt2], ahr[mt], acc[mt][hf * 2 + nt2], 0, 0, 0);
            #pragma unroll
            for (int mt = 0; mt < 2; ++mt)
                #pragma unroll
                for (int nt2 = 0; nt2 < 2; ++nt2)
                    acc[mt][hf * 2 + nt2] = __builtin_amdgcn_mfma_f32_16x16x32_bf16(
                        bh[nt2], alr[mt], acc[mt][hf * 2 + nt2], 0, 0, 0);
            #pragma unroll
            for (int mt = 0; mt < 2; ++mt)
                #pragma unroll
                for (int nt2 = 0; nt2 < 2; ++nt2)
                    acc[mt][hf * 2 + nt2] = __builtin_amdgcn_mfma_f32_16x16x32_bf16(
                        bl[nt2], ahr[mt], acc[mt][hf * 2 + nt2], 0, 0, 0);
        }
        __syncthreads();   // everyone done reading A before overwrite

        // C layout (swapped): m = mt*16 + (lane&15), n = w*64 + nt*16 + quad*4 + r
        f32x4 bias4[4];
        #pragma unroll
        for (int nt = 0; nt < 4; ++nt)
            bias4[nt] = *(const f32x4*)(bias + w * 64 + nt * 16 + quad * 4);

        #pragma unroll
        for (int mt = 0; mt < 2; ++mt)
            #pragma unroll
            for (int nt = 0; nt < 4; ++nt) {
                int m   = mt * 16 + l15;
                int g   = w * 8 + nt * 2 + (quad >> 1);          // col>>3
                int idx = m * HDIM + (((g ^ (m & 31)) * 8) + (quad & 1) * 4);
                bf16x4 hv, lv;
                #pragma unroll
                for (int r = 0; r < 4; ++r) {
                    float v = fmaxf(acc[mt][nt][r] + bias4[nt][r], 0.f);
                    __bf16 h = (__bf16)v;
                    hv[r] = h;
                    lv[r] = (__bf16)(v - (float)h);
                }
                *(bf16x4*)(&Ahi[idx]) = hv;
                *(bf16x4*)(&Alo[idx]) = lv;
            }
        __syncthreads();
    };

    layer(W1i, b1);
    layer(W2i, b2);

    // ---- logits: waves 0,1 each handle one 16-row m-tile (TM=32) ----
    if (w < 2) {
        f32x4 lg = {0.f, 0.f, 0.f, 0.f};
        #pragma unroll
        for (int kc = 0; kc < 8; ++kc) {
            int row = w * 16 + l15;
            int kg  = kc * 4 + quad;
            int kgs = kg ^ (row & 31);
            bf16x8 ah = *(const bf16x8*)(&Ahi[row * HDIM + kgs * 8]);
            bf16x8 al = *(const bf16x8*)(&Alo[row * HDIM + kgs * 8]);
            bf16x8 bh = *(const bf16x8*)(W3h + (kg * KDIM + l15) * 8);
            bf16x8 bl = *(const bf16x8*)(W3l + (kg * KDIM + l15) * 8);
            lg = __builtin_amdgcn_mfma_f32_16x16x32_bf16(ah, bh, lg, 0, 0, 0);
            lg = __builtin_amdgcn_mfma_f32_16x16x32_bf16(al, bh, lg, 0, 0, 0);
            lg = __builtin_amdgcn_mfma_f32_16x16x32_bf16(ah, bl, lg, 0, 0, 0);
        }

        #pragma unroll
        for (int r = 0; r < 4; ++r) {
            float v  = lg[r];
            float mx = v;
            mx = fmaxf(mx, __shfl_xor(mx, 1));
            mx = fmaxf(mx, __shfl_xor(mx, 2));
            mx = fmaxf(mx, __shfl_xor(mx, 4));
            mx = fmaxf(mx, __shfl_xor(mx, 8));
            float e = __expf(v - mx);
            float s = e;
            s += __shfl_xor(s, 1);
            s += __shfl_xor(s, 2);
            s += __shfl_xor(s, 4);
            s += __shfl_xor(s, 8);
            int grow = (int)r0 + w * 16 + quad * 4 + r;
            int mv   = mask[grow];
            float ov = mv ? (e / s) * 0.25f : -2500.0f;   // (-10000)/sqrt(16)
            P[(long)grow * KDIM + l15] = ov;
        }
    }
}

// ---------------------------------------------------------------------------
// Kernel 2 (UNCHANGED): 512 threads = 8 waves = (s-quarter sq, k-half kh).
// ---------------------------------------------------------------------------
__global__ __launch_bounds__(512) void softs_agg_kernel(
    const float* __restrict__ X, const float* __restrict__ tf,
    const float* __restrict__ P, float* __restrict__ out)
{
    __shared__ float wl[SDIM * KDIM];          // 12.8 KB
    __shared__ float tfl[SDIM];                // 0.8 KB
    __shared__ float invk[KDIM];
    __shared__ float red[6 * 8 * HDIM];        // 48 KB: slot (sq-1)*2+kh
    float* psum = red;                         // alias (dead before red use)

    const int tid = threadIdx.x;
    const int b   = blockIdx.x;

    const float* Pb = P + (long)b * SDIM * KDIM;
    float ps = 0.f;
    #pragma unroll
    for (int t = 0; t < 7; ++t) {
        int i = tid + t * 512;
        if (i < SDIM * KDIM) {
            float e = __expf(Pb[i]);
            wl[i] = e;
            ps += e;
        }
    }
    psum[tid] = ps;
    if (tid < SDIM) tfl[tid] = tf[b * SDIM + tid];
    __syncthreads();

    if (tid < KDIM) {
        float s = 0.f;
        #pragma unroll
        for (int g = 0; g < 32; ++g) s += psum[tid + g * 16];   // 512%16==0
        invk[tid] = 1.f / s;
    }
    __syncthreads();

    #pragma unroll
    for (int t = 0; t < 7; ++t) {
        int i = tid + t * 512;
        if (i < SDIM * KDIM) wl[i] *= tfl[i >> 4] * invk[i & 15];
    }
    __syncthreads();

    const int wv = tid >> 6;
    const int sq = wv >> 1;      // s-quarter: [50*sq, 50*sq+50)
    const int kh = wv & 1;       // k-half: k in [8*kh, 8*kh+8)
    const int ln = tid & 63;     // lane -> h-cols 4*ln..4*ln+3

    f32x4 acc[8];
    #pragma unroll
    for (int j = 0; j < 8; ++j) acc[j] = (f32x4){0.f, 0.f, 0.f, 0.f};

    const f32x4* Xb4 = (const f32x4*)(X + (long)b * SDIM * HDIM);
    const f32x4* wl4 = (const f32x4*)wl;
    const int s0 = sq * 50;
    #pragma unroll 5
    for (int si = 0; si < 50; ++si) {
        int s = s0 + si;
        f32x4 x  = Xb4[s * 64 + ln];             // 1KB coalesced per wave
        f32x4 d0 = wl4[s * 4 + 2 * kh + 0];      // wave-uniform LDS b128
        f32x4 d1 = wl4[s * 4 + 2 * kh + 1];
        #pragma unroll
        for (int j = 0; j < 4; ++j) {
            acc[j]     += x * d0[j];             // k = 8kh + j
            acc[4 + j] += x * d1[j];             // k = 8kh + 4 + j
        }
    }

    if (sq > 0) {
        float* rp = red + (((sq - 1) * 2 + kh) * 8) * HDIM;
        #pragma unroll
        for (int j = 0; j < 8; ++j)
            *(f32x4*)(rp + j * HDIM + 4 * ln) = acc[j];
    }
    __syncthreads();
    if (sq == 0) {
        #pragma unroll
        for (int p = 0; p < 3; ++p) {
            const float* rp = red + ((p * 2 + kh) * 8) * HDIM;
            #pragma unroll
            for (int j = 0; j < 8; ++j)
                acc[j] += *(const f32x4*)(rp + j * HDIM + 4 * ln);
        }
        float* ob = out + (long)b * KDIM * HDIM + kh * 8 * HDIM;
        #pragma unroll
        for (int j = 0; j < 8; ++j)
            *(f32x4*)(ob + j * HDIM + 4 * ln) = acc[j];
    }
}

extern "C" void kernel_launch(void* const* d_in, const int* in_sizes, int n_in,
                              void* d_out, int out_size, void* d_ws, size_t ws_size,
                              hipStream_t stream) {
    (void)in_sizes; (void)n_in; (void)out_size; (void)ws_size;
    const float* X    = (const float*)d_in[0];
    const int*   mask = (const int*)  d_in[1];
    const float* tf   = (const float*)d_in[2];
    const float* W1   = (const float*)d_in[3];
    const float* b1   = (const float*)d_in[4];
    const float* W2   = (const float*)d_in[5];
    const float* b2   = (const float*)d_in[6];
    const float* W3   = (const float*)d_in[7];
    float* out = (float*)d_out;

    char* ws = (char*)d_ws;
    float*  P   = (float*)ws;                          // 102400*16*4 = 6,553,600 B
    __bf16* w1i = (__bf16*)(ws + 6553600);             // 131072 elems (interleaved)
    __bf16* w2i = w1i + 131072;
    __bf16* w3h = w2i + 131072;                        // 4096 elems each
    __bf16* w3l = w3h + 4096;

    pack_all<<<528, 256, 0, stream>>>(W1, W2, W3, w1i, w2i, w3h, w3l);
    mlp_softk_mfma<<<NROWS / TM, 256, 0, stream>>>(X, mask, w1i, b1,
                                                   w2i, b2, w3h, w3l, P);
    softs_agg_kernel<<<BDIM, 512, 0, stream>>>(X, tf, P, out);
}